// Round 15
// baseline (72.319 us; speedup 1.0000x reference)
//
#include <hip/hip_runtime.h>
#include <math.h>

#define N        8192
#define BLK      256
#define RPT      2                    // a-points (rows) per thread
#define ROWS_BLK (BLK * RPT)          // 512 rows per block
#define ITILES   (N / ROWS_BLK)       // 16
#define NSLICE   64                   // j-slices per direction
#define JCHUNK   (N / NSLICE)         // 128 b-points per slice
#define HALF     (ITILES * NSLICE)    // 1024 blocks per direction
#define GRID     (2 * HALF)           // 2048 = 8 blocks/CU, 32 waves/CU
#define RBLK     1024
#define SWEEPS   2                    // INSTRUMENTATION: 2x idempotent sweep
                                      // to push dist past the 39.5us fill
                                      // threshold into rocprof's top-5.

typedef float v2f __attribute__((ext_vector_type(2)));

// ---------------------------------------------------- precompute + init ----
// P[0..N) = target {x,y,z,|p|^2}, P[N..2N) = output  (A-role, float4 AoS).
// Ppk: pair-transposed B-role layout, per point-pair group of 8 floats:
//   [x0 x1 y0 y1 z0 z1 w0 w1] -> v2f lanes line up for v_pk_fma_f32.
//   target groups at float offset 0, output groups at 4N.
// dmin[0..2N) = +inf bits.
__global__ __launch_bounds__(BLK) void chamfer_prep_kernel(
        const float* __restrict__ tgt, const float* __restrict__ outp,
        float4* __restrict__ P, float* __restrict__ Ppk,
        unsigned* __restrict__ dmin) {
    int i = blockIdx.x * BLK + (int)threadIdx.x;   // 0 .. 2N-1
    const float* src = (i < N) ? tgt : outp;
    int k = (i < N) ? i : (i - N);
    float x = src[3 * k + 0];
    float y = src[3 * k + 1];
    float z = src[3 * k + 2];
    float n2 = fmaf(x, x, fmaf(y, y, z * z));
    P[i] = make_float4(x, y, z, n2);

    int cbase = (i < N) ? 0 : 4 * N;       // cloud base (floats)
    int g = k >> 1, e = k & 1;
    float* q = Ppk + cbase + 8 * g + e;
    q[0] = x; q[2] = y; q[4] = z; q[6] = n2;

    dmin[i] = 0x7F800000u;  // +inf
}

// ---------------------------------------------------------------- dist ----
// EXACT R11 kernel (best measured: 25.7us total), swept SWEEPS times over
// the same slice. Sweep 2 recomputes and re-atomicMins identical values
// (idempotent -> output unchanged). A pointer launder between sweeps blocks
// cross-sweep CSE. Purpose: dist duration ~40us -> visible in rocprof top-5
// -> first direct counters for the best structure (VALUBusy/Occupancy
// decide issue-bound vs stall-bound vs fixed-overhead).
// d^2 = |a|^2 + (|b|^2 - 2 a.b); |a|^2 commutes with min.
__global__ __launch_bounds__(BLK) void chamfer_dist_kernel(
        const float4* __restrict__ P, const v2f* __restrict__ Ppk,
        unsigned* __restrict__ dmin) {
    int tid = (int)threadIdx.x;
    int bid = (int)blockIdx.x;
    int dir = (bid >= HALF) ? 1 : 0;
    if (dir) bid -= HALF;
    int aoff = dir ? N : 0;                 // A-role cloud (float4 index)
    int bpk  = dir ? 0 : 2 * N;             // B-role cloud base (v2f index)

    int itile = bid / NSLICE;
    int slice = bid % NSLICE;
    int i = itile * ROWS_BLK + tid;         // rows i and i+BLK

    float4 a0 = P[aoff + i];
    float4 a1 = P[aoff + i + BLK];
    float n0x = -2.0f * a0.x, n0y = -2.0f * a0.y, n0z = -2.0f * a0.z;
    float n1x = -2.0f * a1.x, n1y = -2.0f * a1.y, n1z = -2.0f * a1.z;
    v2f ax0 = {n0x, n0x}, ay0 = {n0y, n0y}, az0 = {n0z, n0z};
    v2f ax1 = {n1x, n1x}, ay1 = {n1y, n1y}, az1 = {n1z, n1z};

    const float inf = __builtin_inff();
    float m00 = inf, m01 = inf;   // row 0 accumulators
    float m10 = inf, m11 = inf;   // row 1 accumulators

    uintptr_t bpi = (uintptr_t)(Ppk + bpk + (size_t)slice * (JCHUNK * 2));

    for (int rep = 0; rep < SWEEPS; ++rep) {
        const v2f* __restrict__ bp = (const v2f*)bpi;   // wave-uniform
        #pragma unroll 2
        for (int g = 0; g < JCHUNK / 2; g += 2) {       // 2 pair-groups = 4 pts
            const v2f* q = bp + g * 4;
            v2f X0 = q[0], Y0 = q[1], Z0 = q[2], W0 = q[3];
            v2f X1 = q[4], Y1 = q[5], Z1 = q[6], W1 = q[7];
            v2f u00 = __builtin_elementwise_fma(ax0, X0,
                      __builtin_elementwise_fma(ay0, Y0,
                      __builtin_elementwise_fma(az0, Z0, W0)));
            v2f u01 = __builtin_elementwise_fma(ax0, X1,
                      __builtin_elementwise_fma(ay0, Y1,
                      __builtin_elementwise_fma(az0, Z1, W1)));
            v2f u10 = __builtin_elementwise_fma(ax1, X0,
                      __builtin_elementwise_fma(ay1, Y0,
                      __builtin_elementwise_fma(az1, Z0, W0)));
            v2f u11 = __builtin_elementwise_fma(ax1, X1,
                      __builtin_elementwise_fma(ay1, Y1,
                      __builtin_elementwise_fma(az1, Z1, W1)));
            m00 = fminf(fminf(m00, u00.x), u00.y);
            m01 = fminf(fminf(m01, u01.x), u01.y);
            m10 = fminf(fminf(m10, u10.x), u10.y);
            m11 = fminf(fminf(m11, u11.x), u11.y);
        }
        // opaque: compiler can't prove sweep 2 reads the same data -> no CSE
        asm volatile("" : "+s"(bpi));
    }
    float d20 = fmaxf(a0.w + fminf(m00, m01), 0.0f);
    float d21 = fmaxf(a1.w + fminf(m10, m11), 0.0f);
    atomicMin(&dmin[aoff + i],       __float_as_uint(d20));   // coalesced
    atomicMin(&dmin[aoff + i + BLK], __float_as_uint(d21));   // coalesced
}

// -------------------------------------------------------------- reduce ----
__global__ __launch_bounds__(RBLK) void chamfer_reduce_kernel(
        const unsigned* __restrict__ dmin,
        const int* __restrict__ curp, const int* __restrict__ subp,
        float* __restrict__ out) {
    __shared__ float sh1[RBLK / 64], sh2[RBLK / 64];
    int t = (int)threadIdx.x;
    float s1 = 0.0f, s2 = 0.0f;
    const uint4* da = (const uint4*)dmin;          // dist1 as uint4
    const uint4* db = (const uint4*)(dmin + N);    // dist2 as uint4
    for (int i = t; i < N / 4; i += RBLK) {
        uint4 v1 = da[i], v2 = db[i];
        s1 += sqrtf(__uint_as_float(v1.x)) + sqrtf(__uint_as_float(v1.y))
            + sqrtf(__uint_as_float(v1.z)) + sqrtf(__uint_as_float(v1.w));
        s2 += sqrtf(__uint_as_float(v2.x)) + sqrtf(__uint_as_float(v2.y))
            + sqrtf(__uint_as_float(v2.z)) + sqrtf(__uint_as_float(v2.w));
    }
    #pragma unroll
    for (int off = 32; off > 0; off >>= 1) {
        s1 += __shfl_down(s1, off, 64);
        s2 += __shfl_down(s2, off, 64);
    }
    int wid = t >> 6, lane = t & 63;
    if (lane == 0) { sh1[wid] = s1; sh2[wid] = s2; }
    __syncthreads();
    if (t == 0) {
        float t1 = 0.0f, t2 = 0.0f;
        #pragma unroll
        for (int w = 0; w < RBLK / 64; ++w) { t1 += sh1[w]; t2 += sh2[w]; }
        int e = curp[0] / subp[0];
        double scale = 10.0 / pow(0.99, (double)e);
        out[0] = (float)((((double)t1 + (double)t2) / (double)N) * 0.5 * scale);
    }
}

// ---------------------------------------------------------------- launch ----
extern "C" void kernel_launch(void* const* d_in, const int* in_sizes, int n_in,
                              void* d_out, int out_size, void* d_ws, size_t ws_size,
                              hipStream_t stream) {
    const float* target = (const float*)d_in[0];   // (1, 8192, 3) f32
    const float* output = (const float*)d_in[1];   // (1, 8192, 3) f32
    const int*   curp   = (const int*)d_in[2];
    const int*   subp   = (const int*)d_in[3];
    float* out = (float*)d_out;

    // ws: float4 P[2N] (256KB) | float Ppk[8N] (256KB) | uint dmin[2N] (64KB)
    float4*   P    = (float4*)d_ws;
    float*    Ppk  = (float*)(P + 2 * N);
    unsigned* dmin = (unsigned*)(Ppk + 8 * N);

    chamfer_prep_kernel<<<2 * N / BLK, BLK, 0, stream>>>(target, output, P, Ppk, dmin);
    chamfer_dist_kernel<<<GRID, BLK, 0, stream>>>(P, (const v2f*)Ppk, dmin);
    chamfer_reduce_kernel<<<1, RBLK, 0, stream>>>(dmin, curp, subp, out);
}

// Round 16
// 26.939 us; speedup vs baseline: 2.6845x; 2.6845x over previous
//
#include <hip/hip_runtime.h>
#include <math.h>

#define N      8192
#define BLK    256
#define RPT    8                    // resident b-points per lane
#define BPW    (64 * RPT)           // 512 b-points per wave
#define NB     (N / BPW)            // 16 b-groups
#define NA     (N / 64)             // 128 a-tiles
#define GRID   ((NB * NA) / 4)      // 512 blocks of 4 waves
#define RBLK   1024

// ---------------------------------------------------- precompute + init ----
// P[0..N) = target {x,y,z,|p|^2}; P[N..2N) = output. dmin = +inf bits.
__global__ __launch_bounds__(BLK) void chamfer_prep_kernel(
        const float* __restrict__ tgt, const float* __restrict__ outp,
        float4* __restrict__ P, unsigned* __restrict__ dmin) {
    int i = blockIdx.x * BLK + (int)threadIdx.x;   // 0 .. 2N-1
    const float* src = (i < N) ? tgt : outp;
    int k = (i < N) ? i : (i - N);
    float x = src[3 * k + 0];
    float y = src[3 * k + 1];
    float z = src[3 * k + 2];
    P[i] = make_float4(x, y, z, fmaf(x, x, fmaf(y, y, z * z)));
    dmin[i] = 0x7F800000u;  // +inf
}

// ---------------------------------------------------------------- dist ----
// Register-resident systolic ring. Lane holds 8 B-points (output cloud)
// forever; a 5-dword A-packet {-2x,-2y,-2z,a2,runmin} rotates through the
// wave's 64 lanes via ds_bpermute (__shfl from lane+1). 64 steps x 8 pairs
// per lane = 512 b x 64 a per wave-task, each pair computed ONCE serving
// BOTH chamfer directions (traveling row-min + resident col-min).
// ZERO memory operations in the hot loop -> no shared-fetch serialization
// (the ~80% stall measured in R15). t = (a2 - 2 a.b) + b2 = d^2 exactly.
__global__ __launch_bounds__(BLK) void chamfer_dist_kernel(
        const float4* __restrict__ P, unsigned* __restrict__ dmin) {
    int tid  = (int)threadIdx.x;
    int lane = tid & 63;
    int W    = (int)blockIdx.x * 4 + (tid >> 6);   // global wave id
    int bt   = W % NB;                             // b-group
    int at   = W / NB;                             // a-tile

    // resident B-points (output cloud), coalesced: index bt*BPW + k*64 + lane
    float bx[RPT], by[RPT], bz[RPT], b2[RPT], ca[RPT];
    #pragma unroll
    for (int k = 0; k < RPT; ++k) {
        float4 b = P[N + bt * BPW + k * 64 + lane];
        bx[k] = b.x; by[k] = b.y; bz[k] = b.z; b2[k] = b.w;
        ca[k] = __builtin_inff();
    }

    // own A-packet (target cloud)
    float4 a = P[at * 64 + lane];
    float px = -2.0f * a.x;
    float py = -2.0f * a.y;
    float pz = -2.0f * a.z;
    float pw = a.w;                       // a^2
    float pr = __builtin_inff();          // traveling row-min (d^2)
    int src = (lane + 1) & 63;            // ring: pull from lane+1

    for (int s = 0; s < 64; ++s) {
        #pragma unroll
        for (int k = 0; k < RPT; k += 2) {
            float t0 = fmaf(px, bx[k],     fmaf(py, by[k],
                       fmaf(pz, bz[k],     pw))) + b2[k];
            float t1 = fmaf(px, bx[k + 1], fmaf(py, by[k + 1],
                       fmaf(pz, bz[k + 1], pw))) + b2[k + 1];
            pr        = fminf(fminf(pr, t0), t1);   // v_min3
            ca[k]     = fminf(ca[k],     t0);
            ca[k + 1] = fminf(ca[k + 1], t1);
        }
        px = __shfl(px, src, 64);
        py = __shfl(py, src, 64);
        pz = __shfl(pz, src, 64);
        pw = __shfl(pw, src, 64);
        pr = __shfl(pr, src, 64);
    }

    // packet is home: commit row-min for a-point at*64+lane
    atomicMin(&dmin[at * 64 + lane], __float_as_uint(fmaxf(pr, 0.0f)));
    // commit resident col-mins for this wave's 512 b-points
    #pragma unroll
    for (int k = 0; k < RPT; ++k)
        atomicMin(&dmin[N + bt * BPW + k * 64 + lane],
                  __float_as_uint(fmaxf(ca[k], 0.0f)));
}

// -------------------------------------------------------------- reduce ----
__global__ __launch_bounds__(RBLK) void chamfer_reduce_kernel(
        const unsigned* __restrict__ dmin,
        const int* __restrict__ curp, const int* __restrict__ subp,
        float* __restrict__ out) {
    __shared__ float sh1[RBLK / 64], sh2[RBLK / 64];
    int t = (int)threadIdx.x;
    float s1 = 0.0f, s2 = 0.0f;
    const uint4* da = (const uint4*)dmin;          // dist1 as uint4
    const uint4* db = (const uint4*)(dmin + N);    // dist2 as uint4
    for (int i = t; i < N / 4; i += RBLK) {
        uint4 v1 = da[i], v2 = db[i];
        s1 += sqrtf(__uint_as_float(v1.x)) + sqrtf(__uint_as_float(v1.y))
            + sqrtf(__uint_as_float(v1.z)) + sqrtf(__uint_as_float(v1.w));
        s2 += sqrtf(__uint_as_float(v2.x)) + sqrtf(__uint_as_float(v2.y))
            + sqrtf(__uint_as_float(v2.z)) + sqrtf(__uint_as_float(v2.w));
    }
    #pragma unroll
    for (int off = 32; off > 0; off >>= 1) {
        s1 += __shfl_down(s1, off, 64);
        s2 += __shfl_down(s2, off, 64);
    }
    int wid = t >> 6, lane = t & 63;
    if (lane == 0) { sh1[wid] = s1; sh2[wid] = s2; }
    __syncthreads();
    if (t == 0) {
        float t1 = 0.0f, t2 = 0.0f;
        #pragma unroll
        for (int w = 0; w < RBLK / 64; ++w) { t1 += sh1[w]; t2 += sh2[w]; }
        int e = curp[0] / subp[0];
        double scale = 10.0 / pow(0.99, (double)e);
        out[0] = (float)((((double)t1 + (double)t2) / (double)N) * 0.5 * scale);
    }
}

// ---------------------------------------------------------------- launch ----
extern "C" void kernel_launch(void* const* d_in, const int* in_sizes, int n_in,
                              void* d_out, int out_size, void* d_ws, size_t ws_size,
                              hipStream_t stream) {
    const float* target = (const float*)d_in[0];   // (1, 8192, 3) f32
    const float* output = (const float*)d_in[1];   // (1, 8192, 3) f32
    const int*   curp   = (const int*)d_in[2];
    const int*   subp   = (const int*)d_in[3];
    float* out = (float*)d_out;

    // ws: float4 P[2N] (256KB) | uint dmin[2N] (64KB)
    float4*   P    = (float4*)d_ws;
    unsigned* dmin = (unsigned*)(P + 2 * N);

    chamfer_prep_kernel<<<2 * N / BLK, BLK, 0, stream>>>(target, output, P, dmin);
    chamfer_dist_kernel<<<GRID, BLK, 0, stream>>>(P, dmin);
    chamfer_reduce_kernel<<<1, RBLK, 0, stream>>>(dmin, curp, subp, out);
}